// Round 5
// baseline (314.106 us; speedup 1.0000x reference)
//
#include <hip/hip_runtime.h>

typedef unsigned int uint;
typedef unsigned short ushort;
typedef __attribute__((ext_vector_type(4))) float f32x4;
typedef __attribute__((ext_vector_type(8))) short short8;

__device__ __forceinline__ uint f2bf(float f) {
    uint u = __builtin_bit_cast(uint, f);
    u += 0x7FFFu + ((u >> 16) & 1u);   // round-to-nearest-even
    return u >> 16;
}

// ---- kernel 1: ftime[b][k] = b_proj[k] + sum_t silu(c[b,t]) * W_proj[k,t]
__global__ __launch_bounds__(256) void k_ftime(const float* __restrict__ c,
                                               const float* __restrict__ Wp,
                                               const float* __restrict__ bp,
                                               float* __restrict__ ftime) {
    int blk = blockIdx.x;            // 0..127 : b*16+k
    int b = blk >> 4, k = blk & 15;
    int tid = threadIdx.x;
    const float* cb = c + b * 1024;
    const float* wk = Wp + k * 1024;
    float v = 0.f;
    for (int t = tid; t < 1024; t += 256) {
        float z = cb[t];
        v += (z / (1.f + expf(-z))) * wk[t];
    }
    for (int off = 32; off; off >>= 1) v += __shfl_down(v, off);
    __shared__ float red[4];
    if ((tid & 63) == 0) red[tid >> 6] = v;
    __syncthreads();
    if (tid == 0) ftime[blk] = red[0] + red[1] + red[2] + red[3] + bp[k];
}

// ---- kernel 2: g[b][r] = (1/16) sum_k ftime[b][k] * cos(pi*k*r/8)
__global__ __launch_bounds__(128) void k_g(const float* __restrict__ ftime,
                                           float* __restrict__ g) {
    int t = threadIdx.x;             // 0..127
    int b = t >> 4, r = t & 15;
    float s = 0.f;
    for (int k = 0; k < 16; ++k)
        s += ftime[b * 16 + k] * cosf((float)((k * r) & 15) * 0.39269908169872414f);
    g[t] = s * 0.0625f;
}

// modulate HALF a 4x4 patch: thread holds the full patch (q[0..3] = rows 0..3,
// 4 floats each), computes output rows half*2..half*2+1, writes swizzled bf16.
__device__ __forceinline__ void mod_half(const float (&gv)[16],
                                         const float4 (&q)[4],
                                         ushort* Asp, int hp, int wp, int half) {
    float xin[16] = {q[0].x, q[0].y, q[0].z, q[0].w,
                     q[1].x, q[1].y, q[1].z, q[1].w,
                     q[2].x, q[2].y, q[2].z, q[2].w,
                     q[3].x, q[3].y, q[3].z, q[3].w};
#pragma unroll
    for (int i2 = 0; i2 < 2; ++i2) {
        int i = half * 2 + i2;
        float xo[4];
#pragma unroll
        for (int jj = 0; jj < 4; ++jj) {
            int n = i * 4 + jj;
            float s = 0.f;
#pragma unroll
            for (int m = 0; m < 16; ++m) s += gv[(n - m) & 15] * xin[m];
            xo[jj] = s;
        }
        int row = 4 * hp + i;
        uint lo = f2bf(xo[0]) | (f2bf(xo[1]) << 16);
        uint hi = f2bf(xo[2]) | (f2bf(xo[3]) << 16);
        int off = row * 128 + ((wp * 8) ^ ((row & 7) << 4));
        *(uint2*)((char*)Asp + off) = make_uint2(lo, hi);
    }
}

__device__ __forceinline__ void mfma_step(const ushort* Ap, const ushort* Bp,
                                          int lane, int wr, int wc,
                                          f32x4 (&acc)[2][4]) {
#pragma unroll
    for (int kk = 0; kk < 2; ++kk) {
        const int kb = kk * 64 + ((lane >> 4) << 4);   // byte offset of 16B k-chunk
        short8 av[2], bv[4];
#pragma unroll
        for (int mf = 0; mf < 2; ++mf) {
            int r = wr * 32 + mf * 16 + (lane & 15);
            av[mf] = *(const short8*)((const char*)Ap + r * 128 + (kb ^ ((r & 7) << 4)));
        }
#pragma unroll
        for (int nf = 0; nf < 4; ++nf) {
            int r = wc * 64 + nf * 16 + (lane & 15);
            bv[nf] = *(const short8*)((const char*)Bp + r * 128 + (kb ^ ((r & 7) << 4)));
        }
#pragma unroll
        for (int mf = 0; mf < 2; ++mf)
#pragma unroll
            for (int nf = 0; nf < 4; ++nf)
                acc[mf][nf] = __builtin_amdgcn_mfma_f32_16x16x32_bf16(
                    av[mf], bv[nf], acc[mf][nf], 0, 0, 0);
    }
}

// ---- kernel 3: fused modulate + GEMM, synchronous 2-phase, reg-staged B.
// BM=64 BN=256 BK=64, 512 thr. No global_load_lds, no ws weight image — B is
// loaded fp32 straight from W_lin (issued at phase start so HBM/L2 latency
// hides under the MFMA phase), converted to bf16 and written swizzled to LDS
// in the write phase. Bs double-buffered, As single-buffered. All hazards are
// covered by full __syncthreads drains.
__global__ __launch_bounds__(512, 4) void k_gemm4(
    const float* __restrict__ x,
    const float* __restrict__ Wl,     // (256, 2048) fp32
    const float* __restrict__ blin,
    const float* __restrict__ szv,
    const float* __restrict__ g_ws,
    float* __restrict__ out) {

    __shared__ __align__(16) ushort As[64 * 64];       // 8 KB
    __shared__ __align__(16) ushort Bs[2][256 * 64];   // 2 x 32 KB

    const int tid = threadIdx.x;
    const int lane = tid & 63;
    const int wid = tid >> 6;
    const int m0 = blockIdx.x * 64;
    const int b = m0 >> 12;

    float gv[16];
#pragma unroll
    for (int r = 0; r < 16; ++r) gv[r] = g_ws[b * 16 + r];

    const int wr = wid >> 2, wc = wid & 3;
    f32x4 acc[2][4];
#pragma unroll
    for (int i = 0; i < 2; ++i)
#pragma unroll
        for (int j = 0; j < 4; ++j) acc[i][j] = (f32x4)0.f;

    // half-patch decomposition: pair (2k,2k+1) shares patch k; each computes 2 rows
    const int p = tid >> 1;            // 0..255
    const int hp = p >> 4;             // patch row 0..15
    const int wp = p & 15;             // patch col 0..15
    const int half = tid & 1;
    const float* xbase = x + (size_t)(m0 + 4 * hp) * 2048 + 4 * wp;

    // B staging split: thread handles chunks {tid + 512*it}, chunk -> (row, slot)
    float4 q[4];
    float4 blo[4], bhi[4];

#define STAGE_LOAD(kt) do { \
        const float* wb_ = Wl + (size_t)(kt) * 64; \
        _Pragma("unroll") \
        for (int it = 0; it < 4; ++it) { \
            int chunk = it * 512 + tid; \
            int row_ = chunk >> 3, slot_ = chunk & 7; \
            const float* src_ = wb_ + (size_t)row_ * 2048 + slot_ * 8; \
            blo[it] = *(const float4*)(src_); \
            bhi[it] = *(const float4*)(src_ + 4); \
        } \
    } while (0)

#define STAGE_WRITE(pp) do { \
        _Pragma("unroll") \
        for (int it = 0; it < 4; ++it) { \
            int chunk = it * 512 + tid; \
            int row_ = chunk >> 3, slot_ = chunk & 7; \
            uint4 pk_; \
            pk_.x = f2bf(blo[it].x) | (f2bf(blo[it].y) << 16); \
            pk_.y = f2bf(blo[it].z) | (f2bf(blo[it].w) << 16); \
            pk_.z = f2bf(bhi[it].x) | (f2bf(bhi[it].y) << 16); \
            pk_.w = f2bf(bhi[it].z) | (f2bf(bhi[it].w) << 16); \
            int off_ = row_ * 128 + ((slot_ * 16) ^ ((row_ & 7) << 4)); \
            *(uint4*)((char*)&Bs[pp][0] + off_) = pk_; \
        } \
    } while (0)

#define LOADX(kt) do { \
        const float* xr_ = xbase + (kt) * 64; \
        q[0] = *(const float4*)(xr_); \
        q[1] = *(const float4*)(xr_ + 2048); \
        q[2] = *(const float4*)(xr_ + 4096); \
        q[3] = *(const float4*)(xr_ + 6144); \
    } while (0)

    // prologue: window 0 loaded, converted, modulated
    STAGE_LOAD(0);
    LOADX(0);
    STAGE_WRITE(0);
    mod_half(gv, q, As, hp, wp, half);
    __syncthreads();                       // As(0), Bs[0](0) committed

    for (int t = 0; t < 31; ++t) {
        // compute phase: issue window t+1 loads, then MFMA window t
        STAGE_LOAD(t + 1);
        LOADX(t + 1);
        mfma_step(As, &Bs[t & 1][0], lane, wr, wc, acc);
        __syncthreads();                   // all reads of As / Bs[t&1] done
        // write phase: stage window t+1 into LDS
        STAGE_WRITE((t + 1) & 1);
        mod_half(gv, q, As, hp, wp, half);
        __syncthreads();                   // As(t+1), Bs[(t+1)&1] committed
    }
    // final window 31
    mfma_step(As, &Bs[1][0], lane, wr, wc, acc);

#undef STAGE_LOAD
#undef STAGE_WRITE
#undef LOADX

    // ---- epilogue: out = scale * (acc + b_lin)
#pragma unroll
    for (int nf = 0; nf < 4; ++nf) {
        int col = wc * 64 + nf * 16 + (lane & 15);
        float scale = szv[col] * 45.254833995939045f;  // sqrt(2048)
        float bl = blin[col];
#pragma unroll
        for (int mf = 0; mf < 2; ++mf) {
            int row = m0 + wr * 32 + mf * 16 + ((lane >> 4) << 2);
#pragma unroll
            for (int j = 0; j < 4; ++j)
                out[(size_t)(row + j) * 256 + col] = scale * (acc[mf][nf][j] + bl);
        }
    }
}

extern "C" void kernel_launch(void* const* d_in, const int* in_sizes, int n_in,
                              void* d_out, int out_size, void* d_ws, size_t ws_size,
                              hipStream_t stream) {
    const float* x  = (const float*)d_in[0];   // (8, 4096, 2048)
    const float* c  = (const float*)d_in[1];   // (8, 1024)
    const float* Wp = (const float*)d_in[2];   // (16, 1024)
    const float* bp = (const float*)d_in[3];   // (16,)
    const float* Wl = (const float*)d_in[4];   // (256, 2048)
    const float* bl = (const float*)d_in[5];   // (256,)
    const float* sz = (const float*)d_in[6];   // (256,)
    float* out = (float*)d_out;

    float* wsf = (float*)d_ws;
    float* ftime = wsf;              // 128 floats
    float* g = wsf + 128;            // 128 floats

    k_ftime<<<128, 256, 0, stream>>>(c, Wp, bp, ftime);
    k_g<<<1, 128, 0, stream>>>(ftime, g);
    k_gemm4<<<512, 512, 0, stream>>>(x, Wl, bl, sz, g, out);
}

// Round 8
// 148.750 us; speedup vs baseline: 2.1116x; 2.1116x over previous
//
#include <hip/hip_runtime.h>

typedef unsigned int uint;
typedef unsigned short ushort;
typedef __attribute__((ext_vector_type(4))) float f32x4;
typedef __attribute__((ext_vector_type(8))) short short8;

#define BM 64
#define BN 256
#define BK 64
#define KTOT 2048
#define NSTEP (KTOT / BK)

__device__ __forceinline__ ushort f2bf(float f) {
    uint u = __builtin_bit_cast(uint, f);
    u += 0x7FFFu + ((u >> 16) & 1u);   // round-to-nearest-even
    return (ushort)(u >> 16);
}

// ---- kernel 1: ftime[b][k] = b_proj[k] + sum_t silu(c[b,t]) * W_proj[k,t]
__global__ __launch_bounds__(256) void k_ftime(const float* __restrict__ c,
                                               const float* __restrict__ Wp,
                                               const float* __restrict__ bp,
                                               float* __restrict__ ftime) {
    int blk = blockIdx.x;            // 0..127 : b*16+k
    int b = blk >> 4, k = blk & 15;
    int tid = threadIdx.x;
    const float* cb = c + b * 1024;
    const float* wk = Wp + k * 1024;
    float v = 0.f;
    for (int t = tid; t < 1024; t += 256) {
        float z = cb[t];
        v += (z / (1.f + expf(-z))) * wk[t];
    }
    for (int off = 32; off; off >>= 1) v += __shfl_down(v, off);
    __shared__ float red[4];
    if ((tid & 63) == 0) red[tid >> 6] = v;
    __syncthreads();
    if (tid == 0) ftime[blk] = red[0] + red[1] + red[2] + red[3] + bp[k];
}

// ---- kernel 2: g[b][r] = (1/16) sum_k ftime[b][k] * cos(pi*k*r/8)
__global__ __launch_bounds__(128) void k_g(const float* __restrict__ ftime,
                                           float* __restrict__ g) {
    int t = threadIdx.x;             // 0..127
    int b = t >> 4, r = t & 15;
    float s = 0.f;
    for (int k = 0; k < 16; ++k)
        s += ftime[b * 16 + k] * cosf((float)((k * r) & 15) * 0.39269908169872414f);
    g[t] = s * 0.0625f;
}

// ---- kernel 3: W_lin fp32 -> bf16 (into workspace) — round-0 exact
__global__ __launch_bounds__(256) void k_wcvt(const float* __restrict__ W,
                                              ushort* __restrict__ o) {
    int i = (blockIdx.x * 256 + threadIdx.x) * 4;
    float4 v = *(const float4*)(W + i);
    uint lo = (uint)f2bf(v.x) | ((uint)f2bf(v.y) << 16);
    uint hi = (uint)f2bf(v.z) | ((uint)f2bf(v.w) << 16);
    *(uint2*)(o + i) = make_uint2(lo, hi);
}

// ---- kernel 4: fused modulate + GEMM — round-0 exact structure, with ONE
// change: the A-threads' x loads are issued in the MFMA phase of the PREVIOUS
// window (register prefetch across the barrier) instead of at the top of the
// modulate phase, hiding x's HBM latency under the MFMA phase.
__global__ __launch_bounds__(512, 4) void k_gemm(
    const float* __restrict__ x,
    const float* __restrict__ Wl,     // fp32 W_lin (fallback)
    const ushort* __restrict__ Wb,    // bf16 W_lin (preferred, may be null)
    const float* __restrict__ blin,
    const float* __restrict__ szv,
    const float* __restrict__ g_ws,
    float* __restrict__ out,
    int use_wb) {

    __shared__ __align__(16) ushort As[BM * BK];   // 8 KB  (swizzled)
    __shared__ __align__(16) ushort Bs[BN * BK];   // 32 KB (swizzled)

    const int tid = threadIdx.x;
    const int lane = tid & 63;
    const int wid = tid >> 6;           // 0..7
    const int m0 = blockIdx.x * BM;
    const int b = m0 >> 12;             // 4096 rows per batch

    float gv[16];
#pragma unroll
    for (int r = 0; r < 16; ++r) gv[r] = g_ws[b * 16 + r];

    const int wr = wid >> 2;            // 0..1 : 32-row strip
    const int wc = wid & 3;             // 0..3 : 64-col strip

    f32x4 acc[2][4];
#pragma unroll
    for (int i = 0; i < 2; ++i)
#pragma unroll
        for (int j = 0; j < 4; ++j) acc[i][j] = (f32x4)0.f;

    const int a_hp = (tid & 255) >> 4;  // patch row 0..15
    const int a_wp = tid & 15;          // patch col 0..15
    const float* xbase = x + (size_t)(m0 + 4 * a_hp) * 2048 + 4 * a_wp;

    float4 q0, q1, q2, q3;              // prefetched x patch (A-threads only)

#define LOADX(kt) do { \
        const float* xr_ = xbase + (kt) * 64; \
        q0 = *(const float4*)(xr_); \
        q1 = *(const float4*)(xr_ + 2048); \
        q2 = *(const float4*)(xr_ + 4096); \
        q3 = *(const float4*)(xr_ + 6144); \
    } while (0)

    if (tid < 256) LOADX(0);

    for (int kt = 0; kt < NSTEP; ++kt) {
        const int k0g = kt * BK;
        if (tid < 256) {
            // ---- modulate one 4x4 patch (prefetched in q0..q3) into bf16 A-tile
            float xin[16] = {q0.x, q0.y, q0.z, q0.w, q1.x, q1.y, q1.z, q1.w,
                             q2.x, q2.y, q2.z, q2.w, q3.x, q3.y, q3.z, q3.w};
            float xo[16];
#pragma unroll
            for (int n = 0; n < 16; ++n) {
                float s = 0.f;
#pragma unroll
                for (int m = 0; m < 16; ++m) s += gv[(n - m) & 15] * xin[m];
                xo[n] = s;
            }
#pragma unroll
            for (int i = 0; i < 4; ++i) {
                int row = 4 * a_hp + i;
                uint lo = (uint)f2bf(xo[i * 4 + 0]) | ((uint)f2bf(xo[i * 4 + 1]) << 16);
                uint hi = (uint)f2bf(xo[i * 4 + 2]) | ((uint)f2bf(xo[i * 4 + 3]) << 16);
                int off = row * (BK * 2) + ((a_wp * 8) ^ ((row & 7) << 4));
                *(uint2*)((char*)As + off) = make_uint2(lo, hi);
            }
        } else {
            const int tt = tid - 256;   // 0..255
            if (use_wb) {
#pragma unroll
                for (int it = 0; it < 8; ++it) {
                    int chunk = it * 256 + tt;   // 0..2047
                    int row = chunk >> 3;        // 0..255
                    int c8 = chunk & 7;
                    short8 v = *(const short8*)(Wb + (size_t)row * 2048 + k0g + c8 * 8);
                    int off = row * (BK * 2) + ((c8 * 16) ^ ((row & 7) << 4));
                    *(short8*)((char*)Bs + off) = v;
                }
            } else {
#pragma unroll
                for (int it = 0; it < 16; ++it) {
                    int chunk = it * 256 + tt;   // 0..4095
                    int row = chunk >> 4;
                    int c4 = chunk & 15;
                    float4 v = *(const float4*)(Wl + (size_t)row * 2048 + k0g + c4 * 4);
                    uint lo = (uint)f2bf(v.x) | ((uint)f2bf(v.y) << 16);
                    uint hi = (uint)f2bf(v.z) | ((uint)f2bf(v.w) << 16);
                    int off = row * (BK * 2) + ((c4 * 8) ^ ((row & 7) << 4));
                    *(uint2*)((char*)Bs + off) = make_uint2(lo, hi);
                }
            }
        }
        __syncthreads();

        // issue next window's x loads before the MFMAs (lands during them)
        if (tid < 256 && kt + 1 < NSTEP) LOADX(kt + 1);

#pragma unroll
        for (int kk = 0; kk < 2; ++kk) {
            const int k0 = kk * 32 + ((lane >> 4) << 3);
            short8 a[2], bb[4];
#pragma unroll
            for (int mf = 0; mf < 2; ++mf) {
                int r = wr * 32 + mf * 16 + (lane & 15);
                int off = r * (BK * 2) + (((k0 * 2)) ^ ((r & 7) << 4));
                a[mf] = *(const short8*)((const char*)As + off);
            }
#pragma unroll
            for (int nf = 0; nf < 4; ++nf) {
                int r = wc * 64 + nf * 16 + (lane & 15);
                int off = r * (BK * 2) + (((k0 * 2)) ^ ((r & 7) << 4));
                bb[nf] = *(const short8*)((const char*)Bs + off);
            }
#pragma unroll
            for (int mf = 0; mf < 2; ++mf)
#pragma unroll
                for (int nf = 0; nf < 4; ++nf)
                    acc[mf][nf] = __builtin_amdgcn_mfma_f32_16x16x32_bf16(
                        a[mf], bb[nf], acc[mf][nf], 0, 0, 0);
        }
        __syncthreads();
    }

#undef LOADX

    // ---- epilogue: out = scale * (acc + b_lin)
#pragma unroll
    for (int nf = 0; nf < 4; ++nf) {
        int col = wc * 64 + nf * 16 + (lane & 15);
        float scale = szv[col] * 45.254833995939045f;  // sqrt(2048)
        float bl = blin[col];
#pragma unroll
        for (int mf = 0; mf < 2; ++mf) {
            int row = m0 + wr * 32 + mf * 16 + ((lane >> 4) << 2);
#pragma unroll
            for (int j = 0; j < 4; ++j)
                out[(size_t)(row + j) * 256 + col] = scale * (acc[mf][nf][j] + bl);
        }
    }
}

extern "C" void kernel_launch(void* const* d_in, const int* in_sizes, int n_in,
                              void* d_out, int out_size, void* d_ws, size_t ws_size,
                              hipStream_t stream) {
    const float* x  = (const float*)d_in[0];   // (8, 4096, 2048)
    const float* c  = (const float*)d_in[1];   // (8, 1024)
    const float* Wp = (const float*)d_in[2];   // (16, 1024)
    const float* bp = (const float*)d_in[3];   // (16,)
    const float* Wl = (const float*)d_in[4];   // (256, 2048)
    const float* bl = (const float*)d_in[5];   // (256,)
    const float* sz = (const float*)d_in[6];   // (256,)
    float* out = (float*)d_out;

    float* wsf = (float*)d_ws;
    float* ftime = wsf;          // 128 floats
    float* g = wsf + 128;        // 128 floats
    ushort* wbf = (ushort*)(wsf + 256);
    size_t need = 256 * sizeof(float) + (size_t)256 * 2048 * sizeof(ushort);
    int use_wb = (ws_size >= need) ? 1 : 0;

    k_ftime<<<128, 256, 0, stream>>>(c, Wp, bp, ftime);
    k_g<<<1, 128, 0, stream>>>(ftime, g);
    if (use_wb) k_wcvt<<<512, 256, 0, stream>>>(Wl, wbf);
    k_gemm<<<512, 512, 0, stream>>>(x, Wl, use_wb ? wbf : (const ushort*)nullptr,
                                    bl, sz, g, out, use_wb);
}